// Round 1
// baseline (508.332 us; speedup 1.0000x reference)
//
#include <hip/hip_runtime.h>
#include <hip/hip_bf16.h>

#define NUM_NODES 50000
#define NUM_EDGES 50000
#define NNZ       500000
#define D_IN      256
#define D_OUT     256

// ---------- bf16 helpers (storage format for xl / e_feat intermediates) ----------
static __device__ __forceinline__ float bf2f(unsigned short u) {
    return __uint_as_float(((unsigned)u) << 16);
}
static __device__ __forceinline__ unsigned short f2bf(float f) {
    unsigned u = __float_as_uint(f);
    u += 0x7FFFu + ((u >> 16) & 1u);   // round-to-nearest-even
    return (unsigned short)(u >> 16);
}

// ---------- 1. count: per-edge cardinality, per-node weighted degree, per-node count ----------
__global__ __launch_bounds__(256) void count_kernel(
    const int* __restrict__ node_idx, const int* __restrict__ edge_idx,
    const float* __restrict__ w,
    float* __restrict__ Dv, int* __restrict__ Bc, int* __restrict__ node_cnt)
{
    int i = blockIdx.x * 256 + threadIdx.x;
    if (i >= NNZ) return;
    int n = node_idx[i];
    int e = edge_idx[i];
    atomicAdd(&Bc[e], 1);
    atomicAdd(&node_cnt[n], 1);
    atomicAdd(&Dv[n], w[e]);
}

// ---------- 2. exclusive scan (one block per array; n = 50000, trivial cost) ----------
__global__ __launch_bounds__(1024) void scan_kernel(
    const int* __restrict__ cntE, int* __restrict__ offE,
    const int* __restrict__ cntN, int* __restrict__ offN)
{
    const int n = 50000;
    const int* cnt = (blockIdx.x == 0) ? cntE : cntN;
    int* off       = (blockIdx.x == 0) ? offE : offN;
    __shared__ int sh[1024];
    __shared__ int carry;
    if (threadIdx.x == 0) carry = 0;
    __syncthreads();
    for (int base = 0; base < n; base += 1024) {
        int i = base + (int)threadIdx.x;
        int v = (i < n) ? cnt[i] : 0;
        sh[threadIdx.x] = v;
        __syncthreads();
        for (int s = 1; s < 1024; s <<= 1) {
            int t = ((int)threadIdx.x >= s) ? sh[threadIdx.x - s] : 0;
            __syncthreads();
            sh[threadIdx.x] += t;
            __syncthreads();
        }
        int c = carry;
        if (i < n) off[i] = c + sh[threadIdx.x] - v;   // exclusive
        __syncthreads();
        if (threadIdx.x == 1023) carry = c + sh[1023];
        __syncthreads();
    }
    if (threadIdx.x == 0) off[n] = carry;
}

// ---------- 3. fill CSR adjacency lists via atomic cursors ----------
__global__ __launch_bounds__(256) void fill_kernel(
    const int* __restrict__ node_idx, const int* __restrict__ edge_idx,
    const int* __restrict__ edge_off, const int* __restrict__ node_off,
    int* __restrict__ ecur, int* __restrict__ ncur,
    int* __restrict__ edge_nodes, int* __restrict__ node_edges)
{
    int i = blockIdx.x * 256 + threadIdx.x;
    if (i >= NNZ) return;
    int nd = node_idx[i];
    int e  = edge_idx[i];
    int pe = atomicAdd(&ecur[e], 1);
    edge_nodes[edge_off[e] + pe] = nd;
    int pn = atomicAdd(&ncur[nd], 1);
    node_edges[node_off[nd] + pn] = e;
}

// ---------- 4. GEMM: xl = x @ W  (fp32 compute, bf16 store) ----------
// Block: 256 threads, tile 64 rows x 256 cols (all of N), K-chunks of 16.
// Thread tile: 16 rows x 4 cols (64 accumulators).
__global__ __launch_bounds__(256) void gemm_kernel(
    const float* __restrict__ x, const float* __restrict__ W,
    unsigned short* __restrict__ xl)
{
    constexpr int BM = 64, BK = 16;
    __shared__ float sA[BK][BM + 4];   // x tile, transposed [k][m]; +4 pad keeps 16B align
    __shared__ float sB[BK][D_OUT];    // W tile [k][n]

    const int tid  = threadIdx.x;
    const int m0   = blockIdx.x * BM;
    const int cg   = tid & 63;         // column group (4 cols)
    const int rg   = tid >> 6;         // row group (16 rows)
    const int col0 = cg * 4;
    const int row0 = rg * 16;

    float acc[16][4];
    #pragma unroll
    for (int r = 0; r < 16; ++r)
        #pragma unroll
        for (int c = 0; c < 4; ++c) acc[r][c] = 0.0f;

    for (int k0 = 0; k0 < D_IN; k0 += BK) {
        // stage x tile (transposed): each thread one float4
        {
            int r = tid >> 2, q = tid & 3;
            int gm = m0 + r; if (gm >= NUM_NODES) gm = NUM_NODES - 1;
            float4 v = *(const float4*)(x + (size_t)gm * D_IN + k0 + q * 4);
            sA[q * 4 + 0][r] = v.x;
            sA[q * 4 + 1][r] = v.y;
            sA[q * 4 + 2][r] = v.z;
            sA[q * 4 + 3][r] = v.w;
        }
        // stage W tile: 1024 float4 total, 4 per thread
        #pragma unroll
        for (int i = 0; i < 4; ++i) {
            int idx = tid + i * 256;
            int kk = idx >> 6, n4 = idx & 63;
            float4 v = *(const float4*)(W + (size_t)(k0 + kk) * D_OUT + n4 * 4);
            *(float4*)(&sB[kk][n4 * 4]) = v;
        }
        __syncthreads();

        #pragma unroll
        for (int kk = 0; kk < BK; ++kk) {
            float4 b4 = *(const float4*)(&sB[kk][col0]);
            float a[16];
            #pragma unroll
            for (int q = 0; q < 4; ++q)
                *(float4*)(&a[q * 4]) = *(const float4*)(&sA[kk][row0 + q * 4]);
            float bb[4] = {b4.x, b4.y, b4.z, b4.w};
            #pragma unroll
            for (int r = 0; r < 16; ++r)
                #pragma unroll
                for (int c = 0; c < 4; ++c)
                    acc[r][c] = fmaf(a[r], bb[c], acc[r][c]);
        }
        __syncthreads();
    }

    // epilogue: bf16 store (coalesced 8B/lane)
    #pragma unroll
    for (int r = 0; r < 16; ++r) {
        int gm = m0 + row0 + r;
        if (gm < NUM_NODES) {
            ushort4 u;
            u.x = f2bf(acc[r][0]); u.y = f2bf(acc[r][1]);
            u.z = f2bf(acc[r][2]); u.w = f2bf(acc[r][3]);
            *(ushort4*)(xl + (size_t)gm * D_OUT + col0) = u;
        }
    }
}

// ---------- 5. edge aggregation: e_feat[e] = (1/|e|) * sum_{i in e} xl[i] ----------
// One wave per edge; lane handles 4 consecutive bf16 (8B coalesced row reads).
__global__ __launch_bounds__(256) void edge_agg_kernel(
    const unsigned short* __restrict__ xl,
    const int* __restrict__ edge_off, const int* __restrict__ edge_nodes,
    unsigned short* __restrict__ e_feat)
{
    int e = blockIdx.x * 4 + (threadIdx.x >> 6);
    int lane = threadIdx.x & 63;
    if (e >= NUM_EDGES) return;
    int beg = edge_off[e], end = edge_off[e + 1];
    float ax = 0.f, ay = 0.f, az = 0.f, aw = 0.f;
    for (int j = beg; j < end; ++j) {
        int node = edge_nodes[j];
        ushort4 u = *(const ushort4*)(xl + (size_t)node * D_OUT + lane * 4);
        ax += bf2f(u.x); ay += bf2f(u.y); az += bf2f(u.z); aw += bf2f(u.w);
    }
    float binv = (end > beg) ? 1.0f / (float)(end - beg) : 0.0f;
    ushort4 o;
    o.x = f2bf(ax * binv); o.y = f2bf(ay * binv);
    o.z = f2bf(az * binv); o.w = f2bf(aw * binv);
    *(ushort4*)(e_feat + (size_t)e * D_OUT + lane * 4) = o;
}

// ---------- 6. node aggregation: out[n] = Dinv[n] * sum_{e ∋ n} e_feat[e] + b ----------
__global__ __launch_bounds__(256) void node_agg_kernel(
    const unsigned short* __restrict__ e_feat,
    const int* __restrict__ node_off, const int* __restrict__ node_edges,
    const float* __restrict__ Dv, const float* __restrict__ bias,
    float* __restrict__ out)
{
    int n = blockIdx.x * 4 + (threadIdx.x >> 6);
    int lane = threadIdx.x & 63;
    if (n >= NUM_NODES) return;
    int beg = node_off[n], end = node_off[n + 1];
    float ax = 0.f, ay = 0.f, az = 0.f, aw = 0.f;
    for (int j = beg; j < end; ++j) {
        int e = node_edges[j];
        ushort4 u = *(const ushort4*)(e_feat + (size_t)e * D_OUT + lane * 4);
        ax += bf2f(u.x); ay += bf2f(u.y); az += bf2f(u.z); aw += bf2f(u.w);
    }
    float d = Dv[n];
    float dinv = (d > 0.0f) ? 1.0f / d : 0.0f;
    float4 bv = *(const float4*)(bias + lane * 4);
    float4 o;
    o.x = ax * dinv + bv.x;
    o.y = ay * dinv + bv.y;
    o.z = az * dinv + bv.z;
    o.w = aw * dinv + bv.w;
    *(float4*)(out + (size_t)n * D_OUT + lane * 4) = o;
}

extern "C" void kernel_launch(void* const* d_in, const int* in_sizes, int n_in,
                              void* d_out, int out_size, void* d_ws, size_t ws_size,
                              hipStream_t stream) {
    const float* x    = (const float*)d_in[0];
    const int*   hidx = (const int*)d_in[1];     // [2, NNZ]: row0=node_idx, row1=edge_idx
    const float* w    = (const float*)d_in[2];
    const float* W    = (const float*)d_in[3];
    const float* b    = (const float*)d_in[4];
    const int* node_idx = hidx;
    const int* edge_idx = hidx + NNZ;

    // ---- workspace carve-up (all fully re-initialized every call) ----
    char* ws = (char*)d_ws;
    size_t off = 0;
    auto alloc = [&](size_t bytes) -> void* {
        off = (off + 511) & ~(size_t)511;
        void* p = ws + off;
        off += bytes;
        return p;
    };
    unsigned short* xl     = (unsigned short*)alloc((size_t)NUM_NODES * D_OUT * 2);
    unsigned short* e_feat = (unsigned short*)alloc((size_t)NUM_EDGES * D_OUT * 2);
    char* zblock = (char*)alloc(5 * 50000 * sizeof(int));   // zeroed counters block
    float* Dv       = (float*)(zblock);
    int*   Bc       = (int*)(zblock + 200000);
    int*   node_cnt = (int*)(zblock + 400000);
    int*   ecur     = (int*)(zblock + 600000);
    int*   ncur     = (int*)(zblock + 800000);
    int* edge_off   = (int*)alloc((NUM_EDGES + 1) * sizeof(int));
    int* node_off   = (int*)alloc((NUM_NODES + 1) * sizeof(int));
    int* edge_nodes = (int*)alloc((size_t)NNZ * sizeof(int));
    int* node_edges = (int*)alloc((size_t)NNZ * sizeof(int));

    hipMemsetAsync(zblock, 0, 5 * 50000 * sizeof(int), stream);

    count_kernel<<<(NNZ + 255) / 256, 256, 0, stream>>>(node_idx, edge_idx, w, Dv, Bc, node_cnt);
    scan_kernel<<<2, 1024, 0, stream>>>(Bc, edge_off, node_cnt, node_off);
    fill_kernel<<<(NNZ + 255) / 256, 256, 0, stream>>>(node_idx, edge_idx, edge_off, node_off,
                                                       ecur, ncur, edge_nodes, node_edges);
    gemm_kernel<<<(NUM_NODES + 63) / 64, 256, 0, stream>>>(x, W, xl);
    edge_agg_kernel<<<NUM_EDGES / 4, 256, 0, stream>>>(xl, edge_off, edge_nodes, e_feat);
    node_agg_kernel<<<NUM_NODES / 4, 256, 0, stream>>>(e_feat, node_off, node_edges, Dv, b,
                                                       (float*)d_out);
}

// Round 2
// 360.667 us; speedup vs baseline: 1.4094x; 1.4094x over previous
//
#include <hip/hip_runtime.h>
#include <hip/hip_bf16.h>

#define NUM_NODES 50000
#define NUM_EDGES 50000
#define NNZ       500000
#define D_IN      256
#define D_OUT     256

typedef __attribute__((ext_vector_type(8))) short  bf16x8;
typedef __attribute__((ext_vector_type(4))) float  f32x4;

// ---------- bf16 helpers ----------
static __device__ __forceinline__ float bf2f(unsigned short u) {
    return __uint_as_float(((unsigned)u) << 16);
}
static __device__ __forceinline__ unsigned short f2bf(float f) {
    unsigned u = __float_as_uint(f);
    u += 0x7FFFu + ((u >> 16) & 1u);   // RNE
    return (unsigned short)(u >> 16);
}

// ---------- 1. count ----------
__global__ __launch_bounds__(256) void count_kernel(
    const int* __restrict__ node_idx, const int* __restrict__ edge_idx,
    const float* __restrict__ w,
    float* __restrict__ Dv, int* __restrict__ Bc, int* __restrict__ node_cnt)
{
    int i = blockIdx.x * 256 + threadIdx.x;
    if (i >= NNZ) return;
    int n = node_idx[i];
    int e = edge_idx[i];
    atomicAdd(&Bc[e], 1);
    atomicAdd(&node_cnt[n], 1);
    atomicAdd(&Dv[n], w[e]);
}

// ---------- 2. hierarchical exclusive scan (3 kernels) ----------
// scan1: per-block exclusive scan of 256 elems, emit block sums.
__global__ __launch_bounds__(256) void scan1_kernel(
    const int* __restrict__ cntE, const int* __restrict__ cntN,
    int* __restrict__ offE, int* __restrict__ offN, int* __restrict__ bsums)
{
    const int arr = blockIdx.y;
    const int* cnt = arr ? cntN : cntE;
    int* off       = arr ? offN : offE;
    int tid = threadIdx.x;
    int i = blockIdx.x * 256 + tid;
    int v = (i < 50000) ? cnt[i] : 0;
    __shared__ int sh[256];
    sh[tid] = v;
    __syncthreads();
    for (int s = 1; s < 256; s <<= 1) {
        int t = (tid >= s) ? sh[tid - s] : 0;
        __syncthreads();
        sh[tid] += t;
        __syncthreads();
    }
    if (i < 50000) off[i] = sh[tid] - v;          // block-local exclusive
    if (tid == 255) bsums[arr * 196 + blockIdx.x] = sh[255];
}

// scan2: one block scans the 2x196 block sums (exclusive).
__global__ __launch_bounds__(256) void scan2_kernel(
    const int* __restrict__ bsums, int* __restrict__ bsum_off)
{
    __shared__ int sh[256];
    int tid = threadIdx.x;
    for (int arr = 0; arr < 2; ++arr) {
        int v = (tid < 196) ? bsums[arr * 196 + tid] : 0;
        sh[tid] = v;
        __syncthreads();
        for (int s = 1; s < 256; s <<= 1) {
            int t = (tid >= s) ? sh[tid - s] : 0;
            __syncthreads();
            sh[tid] += t;
            __syncthreads();
        }
        if (tid < 196) bsum_off[arr * 196 + tid] = sh[tid] - v;
        __syncthreads();
    }
}

// scan3: add block offsets, set sentinel totals.
__global__ __launch_bounds__(256) void scan3_kernel(
    const int* __restrict__ bsum_off, int* __restrict__ offE, int* __restrict__ offN)
{
    const int arr = blockIdx.y;
    int* off = arr ? offN : offE;
    int i = blockIdx.x * 256 + threadIdx.x;
    if (i < 50000) off[i] += bsum_off[arr * 196 + blockIdx.x];
    if (blockIdx.x == 0 && threadIdx.x == 0) off[50000] = NNZ;
}

// ---------- 3. fill CSR adjacency ----------
__global__ __launch_bounds__(256) void fill_kernel(
    const int* __restrict__ node_idx, const int* __restrict__ edge_idx,
    const int* __restrict__ edge_off, const int* __restrict__ node_off,
    int* __restrict__ ecur, int* __restrict__ ncur,
    int* __restrict__ edge_nodes, int* __restrict__ node_edges)
{
    int i = blockIdx.x * 256 + threadIdx.x;
    if (i >= NNZ) return;
    int nd = node_idx[i];
    int e  = edge_idx[i];
    int pe = atomicAdd(&ecur[e], 1);
    edge_nodes[edge_off[e] + pe] = nd;
    int pn = atomicAdd(&ncur[nd], 1);
    node_edges[node_off[nd] + pn] = e;
}

// ---------- 4a. transpose W -> Wt[n][k] bf16 ----------
__global__ __launch_bounds__(256) void transpose_w_kernel(
    const float* __restrict__ W, unsigned short* __restrict__ Wt)
{
    int n = blockIdx.x, k = threadIdx.x;
    Wt[n * 256 + k] = f2bf(W[k * 256 + n]);
}

// ---------- 4b. MFMA bf16 GEMM: xl = bf16(x) @ bf16(W), store bf16 ----------
// BM=64 (rows), BN=256 (full N), BK=32; 256 threads = 4 waves; wave wq owns
// n-range [wq*64, wq*64+64). Per wave: 4x4 subtiles of 16x16, acc in f32x4[4][4].
// LDS XOR swizzle slot = part ^ ((row>>1)&3) => all LDS traffic 2-way (free).
__global__ __launch_bounds__(256) void gemm_kernel(
    const float* __restrict__ x, const unsigned short* __restrict__ Wt,
    unsigned short* __restrict__ xl)
{
    __shared__ __align__(16) unsigned short sA[64 * 32];    // 4 KB
    __shared__ __align__(16) unsigned short sB[256 * 32];   // 16 KB

    const int tid  = threadIdx.x;
    const int l    = tid & 63;
    const int wq   = tid >> 6;          // wave id = n-quadrant
    const int quad = l >> 4;
    const int l15  = l & 15;
    const int m0   = blockIdx.x * 64;

    f32x4 acc[4][4];
    #pragma unroll
    for (int i = 0; i < 4; ++i)
        #pragma unroll
        for (int j = 0; j < 4; ++j) acc[i][j] = (f32x4){0.f, 0.f, 0.f, 0.f};

    // A staging assignment: chunk = tid; row = tid>>2 (64 rows), part g = tid&3.
    const int ar = tid >> 2, ag = tid & 3;
    int agm = m0 + ar; if (agm > NUM_NODES - 1) agm = NUM_NODES - 1;
    const float* aptr = x + (size_t)agm * D_IN + ag * 8;
    unsigned short* aout = &sA[ar * 32 + (ag ^ ((ar >> 1) & 3)) * 8];

    for (int k0 = 0; k0 < D_IN; k0 += 32) {
        // stage A (fp32 -> bf16 in-register)
        {
            float4 v0 = *(const float4*)(aptr + k0);
            float4 v1 = *(const float4*)(aptr + k0 + 4);
            bf16x8 av;
            av[0] = (short)f2bf(v0.x); av[1] = (short)f2bf(v0.y);
            av[2] = (short)f2bf(v0.z); av[3] = (short)f2bf(v0.w);
            av[4] = (short)f2bf(v1.x); av[5] = (short)f2bf(v1.y);
            av[6] = (short)f2bf(v1.z); av[7] = (short)f2bf(v1.w);
            *(bf16x8*)aout = av;
        }
        // stage B (Wt bf16, 1024 chunks of 16B, 4 per thread)
        #pragma unroll
        for (int i = 0; i < 4; ++i) {
            int c = i * 256 + tid;
            int row = c >> 2, g = c & 3;
            bf16x8 bv = *(const bf16x8*)(Wt + row * 256 + k0 + g * 8);
            int s = g ^ ((row >> 1) & 3);
            *(bf16x8*)(&sB[row * 32 + s * 8]) = bv;
        }
        __syncthreads();

        bf16x8 af[4], bfr[4];
        #pragma unroll
        for (int mi = 0; mi < 4; ++mi) {
            int r = mi * 16 + l15;
            int s = quad ^ ((r >> 1) & 3);
            af[mi] = *(const bf16x8*)(&sA[r * 32 + s * 8]);
        }
        #pragma unroll
        for (int ni = 0; ni < 4; ++ni) {
            int r = wq * 64 + ni * 16 + l15;
            int s = quad ^ ((r >> 1) & 3);
            bfr[ni] = *(const bf16x8*)(&sB[r * 32 + s * 8]);
        }
        #pragma unroll
        for (int mi = 0; mi < 4; ++mi)
            #pragma unroll
            for (int ni = 0; ni < 4; ++ni)
                acc[mi][ni] = __builtin_amdgcn_mfma_f32_16x16x32_bf16(
                    af[mi], bfr[ni], acc[mi][ni], 0, 0, 0);
        __syncthreads();
    }

    // epilogue: D layout col=lane&15, row=quad*4+reg
    #pragma unroll
    for (int mi = 0; mi < 4; ++mi) {
        #pragma unroll
        for (int ni = 0; ni < 4; ++ni) {
            int col = wq * 64 + ni * 16 + l15;
            #pragma unroll
            for (int r = 0; r < 4; ++r) {
                int m = m0 + mi * 16 + quad * 4 + r;
                if (m < NUM_NODES)
                    xl[(size_t)m * D_OUT + col] = f2bf(acc[mi][ni][r]);
            }
        }
    }
}

// ---------- 5. edge aggregation ----------
__global__ __launch_bounds__(256) void edge_agg_kernel(
    const unsigned short* __restrict__ xl,
    const int* __restrict__ edge_off, const int* __restrict__ edge_nodes,
    unsigned short* __restrict__ e_feat)
{
    int e = blockIdx.x * 4 + (threadIdx.x >> 6);
    int lane = threadIdx.x & 63;
    if (e >= NUM_EDGES) return;
    int beg = edge_off[e], end = edge_off[e + 1];
    float ax = 0.f, ay = 0.f, az = 0.f, aw = 0.f;
    for (int j = beg; j < end; ++j) {
        int node = edge_nodes[j];
        ushort4 u = *(const ushort4*)(xl + (size_t)node * D_OUT + lane * 4);
        ax += bf2f(u.x); ay += bf2f(u.y); az += bf2f(u.z); aw += bf2f(u.w);
    }
    float binv = (end > beg) ? 1.0f / (float)(end - beg) : 0.0f;
    ushort4 o;
    o.x = f2bf(ax * binv); o.y = f2bf(ay * binv);
    o.z = f2bf(az * binv); o.w = f2bf(aw * binv);
    *(ushort4*)(e_feat + (size_t)e * D_OUT + lane * 4) = o;
}

// ---------- 6. node aggregation ----------
__global__ __launch_bounds__(256) void node_agg_kernel(
    const unsigned short* __restrict__ e_feat,
    const int* __restrict__ node_off, const int* __restrict__ node_edges,
    const float* __restrict__ Dv, const float* __restrict__ bias,
    float* __restrict__ out)
{
    int n = blockIdx.x * 4 + (threadIdx.x >> 6);
    int lane = threadIdx.x & 63;
    if (n >= NUM_NODES) return;
    int beg = node_off[n], end = node_off[n + 1];
    float ax = 0.f, ay = 0.f, az = 0.f, aw = 0.f;
    for (int j = beg; j < end; ++j) {
        int e = node_edges[j];
        ushort4 u = *(const ushort4*)(e_feat + (size_t)e * D_OUT + lane * 4);
        ax += bf2f(u.x); ay += bf2f(u.y); az += bf2f(u.z); aw += bf2f(u.w);
    }
    float d = Dv[n];
    float dinv = (d > 0.0f) ? 1.0f / d : 0.0f;
    float4 bv = *(const float4*)(bias + lane * 4);
    float4 o;
    o.x = ax * dinv + bv.x;
    o.y = ay * dinv + bv.y;
    o.z = az * dinv + bv.z;
    o.w = aw * dinv + bv.w;
    *(float4*)(out + (size_t)n * D_OUT + lane * 4) = o;
}

extern "C" void kernel_launch(void* const* d_in, const int* in_sizes, int n_in,
                              void* d_out, int out_size, void* d_ws, size_t ws_size,
                              hipStream_t stream) {
    const float* x    = (const float*)d_in[0];
    const int*   hidx = (const int*)d_in[1];     // [2, NNZ]: row0=node_idx, row1=edge_idx
    const float* w    = (const float*)d_in[2];
    const float* W    = (const float*)d_in[3];
    const float* b    = (const float*)d_in[4];
    const int* node_idx = hidx;
    const int* edge_idx = hidx + NNZ;

    // ---- workspace carve-up ----
    char* ws = (char*)d_ws;
    size_t off = 0;
    auto alloc = [&](size_t bytes) -> void* {
        off = (off + 511) & ~(size_t)511;
        void* p = ws + off;
        off += bytes;
        return p;
    };
    unsigned short* xl     = (unsigned short*)alloc((size_t)NUM_NODES * D_OUT * 2);
    unsigned short* e_feat = (unsigned short*)alloc((size_t)NUM_EDGES * D_OUT * 2);
    char* zblock = (char*)alloc(5 * 50000 * sizeof(int));   // zeroed counters
    float* Dv       = (float*)(zblock);
    int*   Bc       = (int*)(zblock + 200000);
    int*   node_cnt = (int*)(zblock + 400000);
    int*   ecur     = (int*)(zblock + 600000);
    int*   ncur     = (int*)(zblock + 800000);
    int* edge_off   = (int*)alloc((NUM_EDGES + 1) * sizeof(int));
    int* node_off   = (int*)alloc((NUM_NODES + 1) * sizeof(int));
    int* edge_nodes = (int*)alloc((size_t)NNZ * sizeof(int));
    int* node_edges = (int*)alloc((size_t)NNZ * sizeof(int));
    unsigned short* Wt = (unsigned short*)alloc(256 * 256 * 2);
    int* bsums    = (int*)alloc(392 * sizeof(int));
    int* bsum_off = (int*)alloc(392 * sizeof(int));

    hipMemsetAsync(zblock, 0, 5 * 50000 * sizeof(int), stream);

    count_kernel<<<(NNZ + 255) / 256, 256, 0, stream>>>(node_idx, edge_idx, w, Dv, Bc, node_cnt);
    scan1_kernel<<<dim3(196, 2), 256, 0, stream>>>(Bc, node_cnt, edge_off, node_off, bsums);
    scan2_kernel<<<1, 256, 0, stream>>>(bsums, bsum_off);
    scan3_kernel<<<dim3(196, 2), 256, 0, stream>>>(bsum_off, edge_off, node_off);
    fill_kernel<<<(NNZ + 255) / 256, 256, 0, stream>>>(node_idx, edge_idx, edge_off, node_off,
                                                       ecur, ncur, edge_nodes, node_edges);
    transpose_w_kernel<<<256, 256, 0, stream>>>(W, Wt);
    gemm_kernel<<<(NUM_NODES + 63) / 64, 256, 0, stream>>>(x, Wt, xl);
    edge_agg_kernel<<<NUM_EDGES / 4, 256, 0, stream>>>(xl, edge_off, edge_nodes, e_feat);
    node_agg_kernel<<<NUM_NODES / 4, 256, 0, stream>>>(e_feat, node_off, node_edges, Dv, b,
                                                       (float*)d_out);
}

// Round 3
// 317.164 us; speedup vs baseline: 1.6027x; 1.1372x over previous
//
#include <hip/hip_runtime.h>
#include <hip/hip_bf16.h>

#define NUM_NODES 50000
#define NUM_EDGES 50000
#define NNZ       500000
#define D_IN      256
#define D_OUT     256
#define HB        128        // histogram blocks per array
#define HWORDS    25000      // 50000 keys / 2 per 32-bit word

typedef __attribute__((ext_vector_type(8))) short  bf16x8;
typedef __attribute__((ext_vector_type(4))) float  f32x4;

// ---------- bf16 helpers ----------
static __device__ __forceinline__ float bf2f(unsigned short u) {
    return __uint_as_float(((unsigned)u) << 16);
}
static __device__ __forceinline__ unsigned short f2bf(float f) {
    unsigned u = __float_as_uint(f);
    u += 0x7FFFu + ((u >> 16) & 1u);   // RNE
    return (unsigned short)(u >> 16);
}

// ---------- 1. per-block LDS histograms (no global atomics) ----------
// grid (HB, 2): y=0 -> edge keys, y=1 -> node keys. 100 KB LDS = full 50k-bin
// histogram as packed u16 pairs; per-block per-key count <= chunk(3907) so no
// carry into the neighboring halfword.
__global__ __launch_bounds__(256) void hist_kernel(
    const int* __restrict__ node_idx, const int* __restrict__ edge_idx,
    unsigned int* __restrict__ HbE, unsigned int* __restrict__ HbN)
{
    const int arr = blockIdx.y;
    const int* __restrict__ idx = arr ? node_idx : edge_idx;
    unsigned int* __restrict__ Hb = arr ? HbN : HbE;
    __shared__ unsigned int h[HWORDS];
    for (int wdi = threadIdx.x; wdi < HWORDS; wdi += 256) h[wdi] = 0;
    __syncthreads();
    const int chunk = (NNZ + HB - 1) / HB;           // 3907
    int beg = blockIdx.x * chunk;
    int end = min(NNZ, beg + chunk);
    for (int i = beg + (int)threadIdx.x; i < end; i += 256) {
        int k = idx[i];
        atomicAdd(&h[k >> 1], 1u << ((k & 1) * 16));
    }
    __syncthreads();
    unsigned int* out = Hb + (size_t)blockIdx.x * HWORDS;
    for (int wdi = threadIdx.x; wdi < HWORDS; wdi += 256) out[wdi] = h[wdi];
}

// ---------- 2. reduce histograms -> counts ----------
__global__ __launch_bounds__(256) void hreduce_kernel(
    const unsigned int* __restrict__ HbE, const unsigned int* __restrict__ HbN,
    int* __restrict__ Bc, int* __restrict__ node_cnt)
{
    const int arr = blockIdx.y;
    const unsigned int* __restrict__ Hb = arr ? HbN : HbE;
    int* __restrict__ cnt = arr ? node_cnt : Bc;
    int wdi = blockIdx.x * 256 + (int)threadIdx.x;
    if (wdi >= HWORDS) return;
    unsigned int s0 = 0, s1 = 0;
    for (int b = 0; b < HB; ++b) {
        unsigned int u = Hb[(size_t)b * HWORDS + wdi];
        s0 += u & 0xffffu;
        s1 += u >> 16;
    }
    cnt[2 * wdi]     = (int)s0;
    cnt[2 * wdi + 1] = (int)s1;
}

// ---------- 3. hierarchical exclusive scan ----------
__global__ __launch_bounds__(256) void scan1_kernel(
    const int* __restrict__ cntE, const int* __restrict__ cntN,
    int* __restrict__ offE, int* __restrict__ offN, int* __restrict__ bsums)
{
    const int arr = blockIdx.y;
    const int* cnt = arr ? cntN : cntE;
    int* off       = arr ? offN : offE;
    int tid = threadIdx.x;
    int i = blockIdx.x * 256 + tid;
    int v = (i < 50000) ? cnt[i] : 0;
    __shared__ int sh[256];
    sh[tid] = v;
    __syncthreads();
    for (int s = 1; s < 256; s <<= 1) {
        int t = (tid >= s) ? sh[tid - s] : 0;
        __syncthreads();
        sh[tid] += t;
        __syncthreads();
    }
    if (i < 50000) off[i] = sh[tid] - v;
    if (tid == 255) bsums[arr * 196 + blockIdx.x] = sh[255];
}

__global__ __launch_bounds__(256) void scan2_kernel(
    const int* __restrict__ bsums, int* __restrict__ bsum_off)
{
    __shared__ int sh[256];
    int tid = threadIdx.x;
    for (int arr = 0; arr < 2; ++arr) {
        int v = (tid < 196) ? bsums[arr * 196 + tid] : 0;
        sh[tid] = v;
        __syncthreads();
        for (int s = 1; s < 256; s <<= 1) {
            int t = (tid >= s) ? sh[tid - s] : 0;
            __syncthreads();
            sh[tid] += t;
            __syncthreads();
        }
        if (tid < 196) bsum_off[arr * 196 + tid] = sh[tid] - v;
        __syncthreads();
    }
}

__global__ __launch_bounds__(256) void scan3_kernel(
    const int* __restrict__ bsum_off, int* __restrict__ offE, int* __restrict__ offN)
{
    const int arr = blockIdx.y;
    int* off = arr ? offN : offE;
    int i = blockIdx.x * 256 + threadIdx.x;
    if (i < 50000) off[i] += bsum_off[arr * 196 + blockIdx.x];
    if (blockIdx.x == 0 && threadIdx.x == 0) off[50000] = NNZ;
}

// ---------- 4. fill CSR adjacency ----------
__global__ __launch_bounds__(256) void fill_kernel(
    const int* __restrict__ node_idx, const int* __restrict__ edge_idx,
    const int* __restrict__ edge_off, const int* __restrict__ node_off,
    int* __restrict__ ecur, int* __restrict__ ncur,
    int* __restrict__ edge_nodes, int* __restrict__ node_edges)
{
    int i = blockIdx.x * 256 + threadIdx.x;
    if (i >= NNZ) return;
    int nd = node_idx[i];
    int e  = edge_idx[i];
    int pe = atomicAdd(&ecur[e], 1);
    edge_nodes[edge_off[e] + pe] = nd;
    int pn = atomicAdd(&ncur[nd], 1);
    node_edges[node_off[nd] + pn] = e;
}

// ---------- 5a. transpose W -> Wt[n][k] bf16 ----------
__global__ __launch_bounds__(256) void transpose_w_kernel(
    const float* __restrict__ W, unsigned short* __restrict__ Wt)
{
    int n = blockIdx.x, k = threadIdx.x;
    Wt[n * 256 + k] = f2bf(W[k * 256 + n]);
}

// ---------- 5b. MFMA bf16 GEMM: xl = bf16(x) @ bf16(W) ----------
__global__ __launch_bounds__(256) void gemm_kernel(
    const float* __restrict__ x, const unsigned short* __restrict__ Wt,
    unsigned short* __restrict__ xl)
{
    __shared__ __align__(16) unsigned short sA[64 * 32];    // 4 KB
    __shared__ __align__(16) unsigned short sB[256 * 32];   // 16 KB

    const int tid  = threadIdx.x;
    const int l    = tid & 63;
    const int wq   = tid >> 6;
    const int quad = l >> 4;
    const int l15  = l & 15;
    const int m0   = blockIdx.x * 64;

    f32x4 acc[4][4];
    #pragma unroll
    for (int i = 0; i < 4; ++i)
        #pragma unroll
        for (int j = 0; j < 4; ++j) acc[i][j] = (f32x4){0.f, 0.f, 0.f, 0.f};

    const int ar = tid >> 2, ag = tid & 3;
    int agm = m0 + ar; if (agm > NUM_NODES - 1) agm = NUM_NODES - 1;
    const float* aptr = x + (size_t)agm * D_IN + ag * 8;
    unsigned short* aout = &sA[ar * 32 + (ag ^ ((ar >> 1) & 3)) * 8];

    for (int k0 = 0; k0 < D_IN; k0 += 32) {
        {
            float4 v0 = *(const float4*)(aptr + k0);
            float4 v1 = *(const float4*)(aptr + k0 + 4);
            bf16x8 av;
            av[0] = (short)f2bf(v0.x); av[1] = (short)f2bf(v0.y);
            av[2] = (short)f2bf(v0.z); av[3] = (short)f2bf(v0.w);
            av[4] = (short)f2bf(v1.x); av[5] = (short)f2bf(v1.y);
            av[6] = (short)f2bf(v1.z); av[7] = (short)f2bf(v1.w);
            *(bf16x8*)aout = av;
        }
        #pragma unroll
        for (int i = 0; i < 4; ++i) {
            int c = i * 256 + tid;
            int row = c >> 2, g = c & 3;
            bf16x8 bv = *(const bf16x8*)(Wt + row * 256 + k0 + g * 8);
            int s = g ^ ((row >> 1) & 3);
            *(bf16x8*)(&sB[row * 32 + s * 8]) = bv;
        }
        __syncthreads();

        bf16x8 af[4], bfr[4];
        #pragma unroll
        for (int mi = 0; mi < 4; ++mi) {
            int r = mi * 16 + l15;
            int s = quad ^ ((r >> 1) & 3);
            af[mi] = *(const bf16x8*)(&sA[r * 32 + s * 8]);
        }
        #pragma unroll
        for (int ni = 0; ni < 4; ++ni) {
            int r = wq * 64 + ni * 16 + l15;
            int s = quad ^ ((r >> 1) & 3);
            bfr[ni] = *(const bf16x8*)(&sB[r * 32 + s * 8]);
        }
        #pragma unroll
        for (int mi = 0; mi < 4; ++mi)
            #pragma unroll
            for (int ni = 0; ni < 4; ++ni)
                acc[mi][ni] = __builtin_amdgcn_mfma_f32_16x16x32_bf16(
                    af[mi], bfr[ni], acc[mi][ni], 0, 0, 0);
        __syncthreads();
    }

    #pragma unroll
    for (int mi = 0; mi < 4; ++mi) {
        #pragma unroll
        for (int ni = 0; ni < 4; ++ni) {
            int col = wq * 64 + ni * 16 + l15;
            #pragma unroll
            for (int r = 0; r < 4; ++r) {
                int m = m0 + mi * 16 + quad * 4 + r;
                if (m < NUM_NODES)
                    xl[(size_t)m * D_OUT + col] = f2bf(acc[mi][ni][r]);
            }
        }
    }
}

// ---------- 6. edge aggregation ----------
__global__ __launch_bounds__(256) void edge_agg_kernel(
    const unsigned short* __restrict__ xl,
    const int* __restrict__ edge_off, const int* __restrict__ edge_nodes,
    unsigned short* __restrict__ e_feat)
{
    int e = blockIdx.x * 4 + (threadIdx.x >> 6);
    int lane = threadIdx.x & 63;
    if (e >= NUM_EDGES) return;
    int beg = edge_off[e], end = edge_off[e + 1];
    float ax = 0.f, ay = 0.f, az = 0.f, aw = 0.f;
    for (int j = beg; j < end; ++j) {
        int node = edge_nodes[j];
        ushort4 u = *(const ushort4*)(xl + (size_t)node * D_OUT + lane * 4);
        ax += bf2f(u.x); ay += bf2f(u.y); az += bf2f(u.z); aw += bf2f(u.w);
    }
    float binv = (end > beg) ? 1.0f / (float)(end - beg) : 0.0f;
    ushort4 o;
    o.x = f2bf(ax * binv); o.y = f2bf(ay * binv);
    o.z = f2bf(az * binv); o.w = f2bf(aw * binv);
    *(ushort4*)(e_feat + (size_t)e * D_OUT + lane * 4) = o;
}

// ---------- 7. node aggregation (Dv fused: sum of w over incident edges) ----------
__global__ __launch_bounds__(256) void node_agg_kernel(
    const unsigned short* __restrict__ e_feat,
    const int* __restrict__ node_off, const int* __restrict__ node_edges,
    const float* __restrict__ w, const float* __restrict__ bias,
    float* __restrict__ out)
{
    int n = blockIdx.x * 4 + (threadIdx.x >> 6);
    int lane = threadIdx.x & 63;
    if (n >= NUM_NODES) return;
    int beg = node_off[n], end = node_off[n + 1];
    float ax = 0.f, ay = 0.f, az = 0.f, aw = 0.f;
    float dsum = 0.f;
    for (int j = beg; j < end; ++j) {
        int e = node_edges[j];
        dsum += w[e];                                  // broadcast load (uniform)
        ushort4 u = *(const ushort4*)(e_feat + (size_t)e * D_OUT + lane * 4);
        ax += bf2f(u.x); ay += bf2f(u.y); az += bf2f(u.z); aw += bf2f(u.w);
    }
    float dinv = (dsum > 0.0f) ? 1.0f / dsum : 0.0f;
    float4 bv = *(const float4*)(bias + lane * 4);
    float4 o;
    o.x = ax * dinv + bv.x;
    o.y = ay * dinv + bv.y;
    o.z = az * dinv + bv.z;
    o.w = aw * dinv + bv.w;
    *(float4*)(out + (size_t)n * D_OUT + lane * 4) = o;
}

extern "C" void kernel_launch(void* const* d_in, const int* in_sizes, int n_in,
                              void* d_out, int out_size, void* d_ws, size_t ws_size,
                              hipStream_t stream) {
    const float* x    = (const float*)d_in[0];
    const int*   hidx = (const int*)d_in[1];     // [2, NNZ]: row0=node_idx, row1=edge_idx
    const float* w    = (const float*)d_in[2];
    const float* W    = (const float*)d_in[3];
    const float* b    = (const float*)d_in[4];
    const int* node_idx = hidx;
    const int* edge_idx = hidx + NNZ;

    // ---- workspace carve-up ----
    char* ws = (char*)d_ws;
    size_t off = 0;
    auto alloc = [&](size_t bytes) -> void* {
        off = (off + 511) & ~(size_t)511;
        void* p = ws + off;
        off += bytes;
        return p;
    };
    unsigned short* xl     = (unsigned short*)alloc((size_t)NUM_NODES * D_OUT * 2); // 25.6 MB
    unsigned short* e_feat = (unsigned short*)alloc((size_t)NUM_EDGES * D_OUT * 2); // 25.6 MB
    char* zblock = (char*)alloc(2 * 50000 * sizeof(int));   // ecur, ncur (zeroed)
    int*   ecur     = (int*)(zblock);
    int*   ncur     = (int*)(zblock + 200000);
    int* Bc         = (int*)alloc(50000 * sizeof(int));
    int* node_cnt   = (int*)alloc(50000 * sizeof(int));
    int* edge_off   = (int*)alloc((NUM_EDGES + 1) * sizeof(int));
    int* node_off   = (int*)alloc((NUM_NODES + 1) * sizeof(int));
    int* edge_nodes = (int*)alloc((size_t)NNZ * sizeof(int));
    int* node_edges = (int*)alloc((size_t)NNZ * sizeof(int));
    unsigned short* Wt = (unsigned short*)alloc(256 * 256 * 2);
    int* bsums    = (int*)alloc(392 * sizeof(int));
    int* bsum_off = (int*)alloc(392 * sizeof(int));

    // Histogram scratch ALIASED over xl / e_feat (consumed by hreduce before
    // gemm/edge_agg write xl/e_feat): 128 * 25000 u32 = 12.8 MB each.
    unsigned int* HbE = (unsigned int*)xl;
    unsigned int* HbN = (unsigned int*)e_feat;

    hipMemsetAsync(zblock, 0, 2 * 50000 * sizeof(int), stream);

    hist_kernel<<<dim3(HB, 2), 256, 0, stream>>>(node_idx, edge_idx, HbE, HbN);
    hreduce_kernel<<<dim3((HWORDS + 255) / 256, 2), 256, 0, stream>>>(HbE, HbN, Bc, node_cnt);
    scan1_kernel<<<dim3(196, 2), 256, 0, stream>>>(Bc, node_cnt, edge_off, node_off, bsums);
    scan2_kernel<<<1, 256, 0, stream>>>(bsums, bsum_off);
    scan3_kernel<<<dim3(196, 2), 256, 0, stream>>>(bsum_off, edge_off, node_off);
    fill_kernel<<<(NNZ + 255) / 256, 256, 0, stream>>>(node_idx, edge_idx, edge_off, node_off,
                                                       ecur, ncur, edge_nodes, node_edges);
    transpose_w_kernel<<<256, 256, 0, stream>>>(W, Wt);
    gemm_kernel<<<(NUM_NODES + 63) / 64, 256, 0, stream>>>(x, Wt, xl);
    edge_agg_kernel<<<NUM_EDGES / 4, 256, 0, stream>>>(xl, edge_off, edge_nodes, e_feat);
    node_agg_kernel<<<NUM_NODES / 4, 256, 0, stream>>>(e_feat, node_off, node_edges, w, b,
                                                       (float*)d_out);
}

// Round 4
// 254.660 us; speedup vs baseline: 1.9961x; 1.2454x over previous
//
#include <hip/hip_runtime.h>
#include <hip/hip_bf16.h>

#define NUM_NODES 50000
#define NUM_EDGES 50000
#define NNZ       500000
#define D_IN      256
#define D_OUT     256
#define HB        128        // histogram blocks per array
#define HWORDS    25000      // 50000 keys / 2 per 32-bit word
#define CHUNK     3907       // ceil(NNZ / HB)

typedef __attribute__((ext_vector_type(8))) short  bf16x8;
typedef __attribute__((ext_vector_type(4))) float  f32x4;

// ---------- bf16 helpers ----------
static __device__ __forceinline__ float bf2f(unsigned short u) {
    return __uint_as_float(((unsigned)u) << 16);
}
static __device__ __forceinline__ unsigned short f2bf(float f) {
    unsigned u = __float_as_uint(f);
    u += 0x7FFFu + ((u >> 16) & 1u);   // RNE
    return (unsigned short)(u >> 16);
}

// ---------- 1. per-block LDS histograms (no global atomics) ----------
__global__ __launch_bounds__(256) void hist_kernel(
    const int* __restrict__ node_idx, const int* __restrict__ edge_idx,
    unsigned int* __restrict__ HbE, unsigned int* __restrict__ HbN)
{
    const int arr = blockIdx.y;
    const int* __restrict__ idx = arr ? node_idx : edge_idx;
    unsigned int* __restrict__ Hb = arr ? HbN : HbE;
    __shared__ unsigned int h[HWORDS];
    for (int wdi = threadIdx.x; wdi < HWORDS; wdi += 256) h[wdi] = 0;
    __syncthreads();
    int beg = blockIdx.x * CHUNK;
    int end = min(NNZ, beg + CHUNK);
    for (int i = beg + (int)threadIdx.x; i < end; i += 256) {
        int k = idx[i];
        atomicAdd(&h[k >> 1], 1u << ((k & 1) * 16));
    }
    __syncthreads();
    unsigned int* out = Hb + (size_t)blockIdx.x * HWORDS;
    for (int wdi = threadIdx.x; wdi < HWORDS; wdi += 256) out[wdi] = h[wdi];
}

// ---------- 2. reduce histograms -> counts; rewrite Hb as per-block prefix ----------
// After this kernel, Hb[b][word] holds (packed u16) the number of occurrences
// of each key in blocks < b. Per-key totals are ~10 (max ~40) so u16 is safe.
__global__ __launch_bounds__(256) void hreduce_kernel(
    unsigned int* __restrict__ HbE, unsigned int* __restrict__ HbN,
    int* __restrict__ Bc, int* __restrict__ node_cnt)
{
    const int arr = blockIdx.y;
    unsigned int* __restrict__ Hb = arr ? HbN : HbE;
    int* __restrict__ cnt = arr ? node_cnt : Bc;
    int wdi = blockIdx.x * 256 + (int)threadIdx.x;
    if (wdi >= HWORDS) return;
    unsigned int s0 = 0, s1 = 0;
    for (int b = 0; b < HB; ++b) {
        unsigned int u = Hb[(size_t)b * HWORDS + wdi];
        Hb[(size_t)b * HWORDS + wdi] = (s0 & 0xffffu) | (s1 << 16);
        s0 += u & 0xffffu;
        s1 += u >> 16;
    }
    cnt[2 * wdi]     = (int)s0;
    cnt[2 * wdi + 1] = (int)s1;
}

// ---------- 3. hierarchical exclusive scan ----------
__global__ __launch_bounds__(256) void scan1_kernel(
    const int* __restrict__ cntE, const int* __restrict__ cntN,
    int* __restrict__ offE, int* __restrict__ offN, int* __restrict__ bsums)
{
    const int arr = blockIdx.y;
    const int* cnt = arr ? cntN : cntE;
    int* off       = arr ? offN : offE;
    int tid = threadIdx.x;
    int i = blockIdx.x * 256 + tid;
    int v = (i < 50000) ? cnt[i] : 0;
    __shared__ int sh[256];
    sh[tid] = v;
    __syncthreads();
    for (int s = 1; s < 256; s <<= 1) {
        int t = (tid >= s) ? sh[tid - s] : 0;
        __syncthreads();
        sh[tid] += t;
        __syncthreads();
    }
    if (i < 50000) off[i] = sh[tid] - v;
    if (tid == 255) bsums[arr * 196 + blockIdx.x] = sh[255];
}

__global__ __launch_bounds__(256) void scan2_kernel(
    const int* __restrict__ bsums, int* __restrict__ bsum_off)
{
    __shared__ int sh[256];
    int tid = threadIdx.x;
    for (int arr = 0; arr < 2; ++arr) {
        int v = (tid < 196) ? bsums[arr * 196 + tid] : 0;
        sh[tid] = v;
        __syncthreads();
        for (int s = 1; s < 256; s <<= 1) {
            int t = (tid >= s) ? sh[tid - s] : 0;
            __syncthreads();
            sh[tid] += t;
            __syncthreads();
        }
        if (tid < 196) bsum_off[arr * 196 + tid] = sh[tid] - v;
        __syncthreads();
    }
}

__global__ __launch_bounds__(256) void scan3_kernel(
    const int* __restrict__ bsum_off, int* __restrict__ offE, int* __restrict__ offN)
{
    const int arr = blockIdx.y;
    int* off = arr ? offN : offE;
    int i = blockIdx.x * 256 + threadIdx.x;
    if (i < 50000) off[i] += bsum_off[arr * 196 + blockIdx.x];
    if (blockIdx.x == 0 && threadIdx.x == 0) off[50000] = NNZ;
}

// ---------- 4. atomic-free CSR fill using per-block prefix cursors in LDS ----------
// grid (HB, 2). LDS cursor initialized to Hb prefix; LDS atomicAdd yields a
// globally-unique rank; slot = off[key] + rank. No global atomics.
__global__ __launch_bounds__(256) void fill_kernel(
    const int* __restrict__ node_idx, const int* __restrict__ edge_idx,
    const unsigned int* __restrict__ HbE, const unsigned int* __restrict__ HbN,
    const int* __restrict__ edge_off, const int* __restrict__ node_off,
    int* __restrict__ edge_nodes, int* __restrict__ node_edges)
{
    const int arr = blockIdx.y;
    const int* __restrict__ key = arr ? node_idx : edge_idx;
    const int* __restrict__ val = arr ? edge_idx : node_idx;
    const unsigned int* __restrict__ Hb = arr ? HbN : HbE;
    const int* __restrict__ off = arr ? node_off : edge_off;
    int* __restrict__ out       = arr ? node_edges : edge_nodes;

    __shared__ unsigned int h[HWORDS];
    const unsigned int* hrow = Hb + (size_t)blockIdx.x * HWORDS;
    for (int wdi = threadIdx.x; wdi < HWORDS; wdi += 256) h[wdi] = hrow[wdi];
    __syncthreads();

    int beg = blockIdx.x * CHUNK;
    int end = min(NNZ, beg + CHUNK);
    for (int i = beg + (int)threadIdx.x; i < end; i += 256) {
        int k = key[i];
        int sh = (k & 1) * 16;
        unsigned int old = atomicAdd(&h[k >> 1], 1u << sh);
        int rank = (int)((old >> sh) & 0xffffu);
        out[off[k] + rank] = val[i];
    }
}

// ---------- 5a. transpose W -> Wt[n][k] bf16 ----------
__global__ __launch_bounds__(256) void transpose_w_kernel(
    const float* __restrict__ W, unsigned short* __restrict__ Wt)
{
    int n = blockIdx.x, k = threadIdx.x;
    Wt[n * 256 + k] = f2bf(W[k * 256 + n]);
}

// ---------- 5b. MFMA bf16 GEMM: xl = bf16(x) @ bf16(W) ----------
__global__ __launch_bounds__(256) void gemm_kernel(
    const float* __restrict__ x, const unsigned short* __restrict__ Wt,
    unsigned short* __restrict__ xl)
{
    __shared__ __align__(16) unsigned short sA[64 * 32];    // 4 KB
    __shared__ __align__(16) unsigned short sB[256 * 32];   // 16 KB

    const int tid  = threadIdx.x;
    const int l    = tid & 63;
    const int wq   = tid >> 6;
    const int quad = l >> 4;
    const int l15  = l & 15;
    const int m0   = blockIdx.x * 64;

    f32x4 acc[4][4];
    #pragma unroll
    for (int i = 0; i < 4; ++i)
        #pragma unroll
        for (int j = 0; j < 4; ++j) acc[i][j] = (f32x4){0.f, 0.f, 0.f, 0.f};

    const int ar = tid >> 2, ag = tid & 3;
    int agm = m0 + ar; if (agm > NUM_NODES - 1) agm = NUM_NODES - 1;
    const float* aptr = x + (size_t)agm * D_IN + ag * 8;
    unsigned short* aout = &sA[ar * 32 + (ag ^ ((ar >> 1) & 3)) * 8];

    for (int k0 = 0; k0 < D_IN; k0 += 32) {
        {
            float4 v0 = *(const float4*)(aptr + k0);
            float4 v1 = *(const float4*)(aptr + k0 + 4);
            bf16x8 av;
            av[0] = (short)f2bf(v0.x); av[1] = (short)f2bf(v0.y);
            av[2] = (short)f2bf(v0.z); av[3] = (short)f2bf(v0.w);
            av[4] = (short)f2bf(v1.x); av[5] = (short)f2bf(v1.y);
            av[6] = (short)f2bf(v1.z); av[7] = (short)f2bf(v1.w);
            *(bf16x8*)aout = av;
        }
        #pragma unroll
        for (int i = 0; i < 4; ++i) {
            int c = i * 256 + tid;
            int row = c >> 2, g = c & 3;
            bf16x8 bv = *(const bf16x8*)(Wt + row * 256 + k0 + g * 8);
            int s = g ^ ((row >> 1) & 3);
            *(bf16x8*)(&sB[row * 32 + s * 8]) = bv;
        }
        __syncthreads();

        bf16x8 af[4], bfr[4];
        #pragma unroll
        for (int mi = 0; mi < 4; ++mi) {
            int r = mi * 16 + l15;
            int s = quad ^ ((r >> 1) & 3);
            af[mi] = *(const bf16x8*)(&sA[r * 32 + s * 8]);
        }
        #pragma unroll
        for (int ni = 0; ni < 4; ++ni) {
            int r = wq * 64 + ni * 16 + l15;
            int s = quad ^ ((r >> 1) & 3);
            bfr[ni] = *(const bf16x8*)(&sB[r * 32 + s * 8]);
        }
        #pragma unroll
        for (int mi = 0; mi < 4; ++mi)
            #pragma unroll
            for (int ni = 0; ni < 4; ++ni)
                acc[mi][ni] = __builtin_amdgcn_mfma_f32_16x16x32_bf16(
                    af[mi], bfr[ni], acc[mi][ni], 0, 0, 0);
        __syncthreads();
    }

    #pragma unroll
    for (int mi = 0; mi < 4; ++mi) {
        #pragma unroll
        for (int ni = 0; ni < 4; ++ni) {
            int col = wq * 64 + ni * 16 + l15;
            #pragma unroll
            for (int r = 0; r < 4; ++r) {
                int m = m0 + mi * 16 + quad * 4 + r;
                if (m < NUM_NODES)
                    xl[(size_t)m * D_OUT + col] = f2bf(acc[mi][ni][r]);
            }
        }
    }
}

// ---------- 6. edge aggregation (4-deep ILP pipeline) ----------
__global__ __launch_bounds__(256) void edge_agg_kernel(
    const unsigned short* __restrict__ xl,
    const int* __restrict__ edge_off, const int* __restrict__ edge_nodes,
    unsigned short* __restrict__ e_feat)
{
    int e = blockIdx.x * 4 + (threadIdx.x >> 6);
    int lane = threadIdx.x & 63;
    if (e >= NUM_EDGES) return;
    int beg = edge_off[e], end = edge_off[e + 1];
    float ax = 0.f, ay = 0.f, az = 0.f, aw = 0.f;
    int j = beg;
    for (; j + 4 <= end; j += 4) {
        int n0 = edge_nodes[j];
        int n1 = edge_nodes[j + 1];
        int n2 = edge_nodes[j + 2];
        int n3 = edge_nodes[j + 3];
        ushort4 u0 = *(const ushort4*)(xl + (size_t)n0 * D_OUT + lane * 4);
        ushort4 u1 = *(const ushort4*)(xl + (size_t)n1 * D_OUT + lane * 4);
        ushort4 u2 = *(const ushort4*)(xl + (size_t)n2 * D_OUT + lane * 4);
        ushort4 u3 = *(const ushort4*)(xl + (size_t)n3 * D_OUT + lane * 4);
        ax += bf2f(u0.x) + bf2f(u1.x) + bf2f(u2.x) + bf2f(u3.x);
        ay += bf2f(u0.y) + bf2f(u1.y) + bf2f(u2.y) + bf2f(u3.y);
        az += bf2f(u0.z) + bf2f(u1.z) + bf2f(u2.z) + bf2f(u3.z);
        aw += bf2f(u0.w) + bf2f(u1.w) + bf2f(u2.w) + bf2f(u3.w);
    }
    for (; j < end; ++j) {
        int node = edge_nodes[j];
        ushort4 u = *(const ushort4*)(xl + (size_t)node * D_OUT + lane * 4);
        ax += bf2f(u.x); ay += bf2f(u.y); az += bf2f(u.z); aw += bf2f(u.w);
    }
    float binv = (end > beg) ? 1.0f / (float)(end - beg) : 0.0f;
    ushort4 o;
    o.x = f2bf(ax * binv); o.y = f2bf(ay * binv);
    o.z = f2bf(az * binv); o.w = f2bf(aw * binv);
    *(ushort4*)(e_feat + (size_t)e * D_OUT + lane * 4) = o;
}

// ---------- 7. node aggregation (Dv fused, 4-deep ILP pipeline) ----------
__global__ __launch_bounds__(256) void node_agg_kernel(
    const unsigned short* __restrict__ e_feat,
    const int* __restrict__ node_off, const int* __restrict__ node_edges,
    const float* __restrict__ w, const float* __restrict__ bias,
    float* __restrict__ out)
{
    int n = blockIdx.x * 4 + (threadIdx.x >> 6);
    int lane = threadIdx.x & 63;
    if (n >= NUM_NODES) return;
    int beg = node_off[n], end = node_off[n + 1];
    float ax = 0.f, ay = 0.f, az = 0.f, aw = 0.f;
    float dsum = 0.f;
    int j = beg;
    for (; j + 4 <= end; j += 4) {
        int e0 = node_edges[j];
        int e1 = node_edges[j + 1];
        int e2 = node_edges[j + 2];
        int e3 = node_edges[j + 3];
        ushort4 u0 = *(const ushort4*)(e_feat + (size_t)e0 * D_OUT + lane * 4);
        ushort4 u1 = *(const ushort4*)(e_feat + (size_t)e1 * D_OUT + lane * 4);
        ushort4 u2 = *(const ushort4*)(e_feat + (size_t)e2 * D_OUT + lane * 4);
        ushort4 u3 = *(const ushort4*)(e_feat + (size_t)e3 * D_OUT + lane * 4);
        dsum += w[e0] + w[e1] + w[e2] + w[e3];
        ax += bf2f(u0.x) + bf2f(u1.x) + bf2f(u2.x) + bf2f(u3.x);
        ay += bf2f(u0.y) + bf2f(u1.y) + bf2f(u2.y) + bf2f(u3.y);
        az += bf2f(u0.z) + bf2f(u1.z) + bf2f(u2.z) + bf2f(u3.z);
        aw += bf2f(u0.w) + bf2f(u1.w) + bf2f(u2.w) + bf2f(u3.w);
    }
    for (; j < end; ++j) {
        int e = node_edges[j];
        dsum += w[e];
        ushort4 u = *(const ushort4*)(e_feat + (size_t)e * D_OUT + lane * 4);
        ax += bf2f(u.x); ay += bf2f(u.y); az += bf2f(u.z); aw += bf2f(u.w);
    }
    float dinv = (dsum > 0.0f) ? 1.0f / dsum : 0.0f;
    float4 bv = *(const float4*)(bias + lane * 4);
    float4 o;
    o.x = ax * dinv + bv.x;
    o.y = ay * dinv + bv.y;
    o.z = az * dinv + bv.z;
    o.w = aw * dinv + bv.w;
    *(float4*)(out + (size_t)n * D_OUT + lane * 4) = o;
}

extern "C" void kernel_launch(void* const* d_in, const int* in_sizes, int n_in,
                              void* d_out, int out_size, void* d_ws, size_t ws_size,
                              hipStream_t stream) {
    const float* x    = (const float*)d_in[0];
    const int*   hidx = (const int*)d_in[1];     // [2, NNZ]: row0=node_idx, row1=edge_idx
    const float* w    = (const float*)d_in[2];
    const float* W    = (const float*)d_in[3];
    const float* b    = (const float*)d_in[4];
    const int* node_idx = hidx;
    const int* edge_idx = hidx + NNZ;

    // ---- workspace carve-up ----
    char* ws = (char*)d_ws;
    size_t off = 0;
    auto alloc = [&](size_t bytes) -> void* {
        off = (off + 511) & ~(size_t)511;
        void* p = ws + off;
        off += bytes;
        return p;
    };
    unsigned short* xl     = (unsigned short*)alloc((size_t)NUM_NODES * D_OUT * 2); // 25.6 MB
    unsigned short* e_feat = (unsigned short*)alloc((size_t)NUM_EDGES * D_OUT * 2); // 25.6 MB
    int* Bc         = (int*)alloc(50000 * sizeof(int));
    int* node_cnt   = (int*)alloc(50000 * sizeof(int));
    int* edge_off   = (int*)alloc((NUM_EDGES + 1) * sizeof(int));
    int* node_off   = (int*)alloc((NUM_NODES + 1) * sizeof(int));
    int* edge_nodes = (int*)alloc((size_t)NNZ * sizeof(int));
    int* node_edges = (int*)alloc((size_t)NNZ * sizeof(int));
    unsigned short* Wt = (unsigned short*)alloc(256 * 256 * 2);
    int* bsums    = (int*)alloc(392 * sizeof(int));
    int* bsum_off = (int*)alloc(392 * sizeof(int));

    // Histogram/prefix scratch ALIASED over xl / e_feat (fully consumed by
    // fill_kernel before gemm/edge_agg write xl/e_feat).
    unsigned int* HbE = (unsigned int*)xl;
    unsigned int* HbN = (unsigned int*)e_feat;

    hist_kernel<<<dim3(HB, 2), 256, 0, stream>>>(node_idx, edge_idx, HbE, HbN);
    hreduce_kernel<<<dim3((HWORDS + 255) / 256, 2), 256, 0, stream>>>(HbE, HbN, Bc, node_cnt);
    scan1_kernel<<<dim3(196, 2), 256, 0, stream>>>(Bc, node_cnt, edge_off, node_off, bsums);
    scan2_kernel<<<1, 256, 0, stream>>>(bsums, bsum_off);
    scan3_kernel<<<dim3(196, 2), 256, 0, stream>>>(bsum_off, edge_off, node_off);
    fill_kernel<<<dim3(HB, 2), 256, 0, stream>>>(node_idx, edge_idx, HbE, HbN,
                                                 edge_off, node_off, edge_nodes, node_edges);
    transpose_w_kernel<<<256, 256, 0, stream>>>(W, Wt);
    gemm_kernel<<<(NUM_NODES + 63) / 64, 256, 0, stream>>>(x, Wt, xl);
    edge_agg_kernel<<<NUM_EDGES / 4, 256, 0, stream>>>(xl, edge_off, edge_nodes, e_feat);
    node_agg_kernel<<<NUM_NODES / 4, 256, 0, stream>>>(e_feat, node_off, node_edges, w, b,
                                                       (float*)d_out);
}

// Round 5
// 253.725 us; speedup vs baseline: 2.0035x; 1.0037x over previous
//
#include <hip/hip_runtime.h>
#include <hip/hip_bf16.h>

#define NUM_NODES 50000
#define NUM_EDGES 50000
#define NNZ       500000
#define D_IN      256
#define D_OUT     256
#define HB        128        // histogram blocks per array
#define HWORDS    25000      // 50000 keys / 2 per 32-bit word
#define CHUNK     3907       // ceil(NNZ / HB)
#define NBLK      196        // ceil(50000 / 256) scan chunks

typedef __attribute__((ext_vector_type(8))) short  bf16x8;
typedef __attribute__((ext_vector_type(4))) float  f32x4;

// ---------- bf16 helpers ----------
static __device__ __forceinline__ float bf2f(unsigned short u) {
    return __uint_as_float(((unsigned)u) << 16);
}
static __device__ __forceinline__ unsigned short f2bf(float f) {
    unsigned u = __float_as_uint(f);
    u += 0x7FFFu + ((u >> 16) & 1u);   // RNE
    return (unsigned short)(u >> 16);
}

// ---------- 1. per-block LDS histograms + folded W-transpose ----------
// grid (HB, 2). Each of the 256 blocks also transposes one column of W.
__global__ __launch_bounds__(256) void hist_kernel(
    const int* __restrict__ node_idx, const int* __restrict__ edge_idx,
    unsigned int* __restrict__ HbE, unsigned int* __restrict__ HbN,
    const float* __restrict__ W, unsigned short* __restrict__ Wt)
{
    const int arr = blockIdx.y;
    // folded transpose: block (bx, arr) handles W column n = arr*128+bx
    {
        int n = arr * HB + blockIdx.x;           // 0..255
        Wt[n * 256 + threadIdx.x] = f2bf(W[(size_t)threadIdx.x * 256 + n]);
    }
    const int* __restrict__ idx = arr ? node_idx : edge_idx;
    unsigned int* __restrict__ Hb = arr ? HbN : HbE;
    __shared__ unsigned int h[HWORDS];
    for (int wdi = threadIdx.x; wdi < HWORDS; wdi += 256) h[wdi] = 0;
    __syncthreads();
    int beg = blockIdx.x * CHUNK;
    int end = min(NNZ, beg + CHUNK);
    for (int i = beg + (int)threadIdx.x; i < end; i += 256) {
        int k = idx[i];
        atomicAdd(&h[k >> 1], 1u << ((k & 1) * 16));
    }
    __syncthreads();
    unsigned int* out = Hb + (size_t)blockIdx.x * HWORDS;
    for (int wdi = threadIdx.x; wdi < HWORDS; wdi += 256) out[wdi] = h[wdi];
}

// ---------- 2. reduce histograms -> counts; rewrite Hb as per-block prefix ----------
__global__ __launch_bounds__(256) void hreduce_kernel(
    unsigned int* __restrict__ HbE, unsigned int* __restrict__ HbN,
    int* __restrict__ Bc, int* __restrict__ node_cnt)
{
    const int arr = blockIdx.y;
    unsigned int* __restrict__ Hb = arr ? HbN : HbE;
    int* __restrict__ cnt = arr ? node_cnt : Bc;
    int wdi = blockIdx.x * 256 + (int)threadIdx.x;
    if (wdi >= HWORDS) return;
    unsigned int s0 = 0, s1 = 0;
    for (int b = 0; b < HB; ++b) {
        unsigned int u = Hb[(size_t)b * HWORDS + wdi];
        Hb[(size_t)b * HWORDS + wdi] = (s0 & 0xffffu) | (s1 << 16);
        s0 += u & 0xffffu;
        s1 += u >> 16;
    }
    cnt[2 * wdi]     = (int)s0;
    cnt[2 * wdi + 1] = (int)s1;
}

// ---------- 3. scan stage 1: per-256-chunk exclusive scan + chunk sums ----------
__global__ __launch_bounds__(256) void scan1_kernel(
    const int* __restrict__ cntE, const int* __restrict__ cntN,
    int* __restrict__ offE, int* __restrict__ offN, int* __restrict__ bsums)
{
    const int arr = blockIdx.y;
    const int* cnt = arr ? cntN : cntE;
    int* off       = arr ? offN : offE;
    int tid = threadIdx.x;
    int i = blockIdx.x * 256 + tid;
    int v = (i < 50000) ? cnt[i] : 0;
    __shared__ int sh[256];
    sh[tid] = v;
    __syncthreads();
    for (int s = 1; s < 256; s <<= 1) {
        int t = (tid >= s) ? sh[tid - s] : 0;
        __syncthreads();
        sh[tid] += t;
        __syncthreads();
    }
    if (i < 50000) off[i] = sh[tid] - v;           // chunk-local exclusive
    if (tid == 255) bsums[arr * NBLK + blockIdx.x] = sh[255];
}

// ---------- 4. scan stage 2: scan chunk sums; write off[50000] sentinels ----------
// Consumers compute global offset as off[i] + bsum_off[arr][i>>8]; sentinel is
// chosen so that off[50000] + bsum_off[195] == NNZ.
__global__ __launch_bounds__(256) void scan2_kernel(
    const int* __restrict__ bsums, int* __restrict__ bsum_off,
    int* __restrict__ offE, int* __restrict__ offN)
{
    __shared__ int sh[256];
    int tid = threadIdx.x;
    for (int arr = 0; arr < 2; ++arr) {
        int v = (tid < NBLK) ? bsums[arr * NBLK + tid] : 0;
        sh[tid] = v;
        __syncthreads();
        for (int s = 1; s < 256; s <<= 1) {
            int t = (tid >= s) ? sh[tid - s] : 0;
            __syncthreads();
            sh[tid] += t;
            __syncthreads();
        }
        if (tid < NBLK) bsum_off[arr * NBLK + tid] = sh[tid] - v;
        if (tid == NBLK - 1) {
            int* off = arr ? offN : offE;
            off[50000] = NNZ - (sh[tid] - v);      // so off[50000]+bs[195]==NNZ
        }
        __syncthreads();
    }
}

// ---------- 5. atomic-free CSR fill (scan3 fused: adds bsum_off here) ----------
__global__ __launch_bounds__(256) void fill_kernel(
    const int* __restrict__ node_idx, const int* __restrict__ edge_idx,
    const unsigned int* __restrict__ HbE, const unsigned int* __restrict__ HbN,
    const int* __restrict__ edge_off, const int* __restrict__ node_off,
    const int* __restrict__ bsum_off,
    int* __restrict__ edge_nodes, int* __restrict__ node_edges)
{
    const int arr = blockIdx.y;
    const int* __restrict__ key = arr ? node_idx : edge_idx;
    const int* __restrict__ val = arr ? edge_idx : node_idx;
    const unsigned int* __restrict__ Hb = arr ? HbN : HbE;
    const int* __restrict__ off = arr ? node_off : edge_off;
    const int* __restrict__ bs  = bsum_off + arr * NBLK;
    int* __restrict__ out       = arr ? node_edges : edge_nodes;

    __shared__ unsigned int h[HWORDS];
    const unsigned int* hrow = Hb + (size_t)blockIdx.x * HWORDS;
    for (int wdi = threadIdx.x; wdi < HWORDS; wdi += 256) h[wdi] = hrow[wdi];
    __syncthreads();

    int beg = blockIdx.x * CHUNK;
    int end = min(NNZ, beg + CHUNK);
    for (int i = beg + (int)threadIdx.x; i < end; i += 256) {
        int k = key[i];
        int sh = (k & 1) * 16;
        unsigned int old = atomicAdd(&h[k >> 1], 1u << sh);
        int rank = (int)((old >> sh) & 0xffffu);
        out[off[k] + bs[k >> 8] + rank] = val[i];
    }
}

// ---------- 6. MFMA bf16 GEMM v2: xl = bf16(x) @ bf16(W) ----------
// BM=32, BN=256, 256 thr = 4 waves (wave = n-quadrant of 64 cols).
// Full A tile (32x256) staged to LDS once in prologue; B double-buffered in
// LDS with register prefetch issued AFTER the per-iter barrier so the
// barrier's vmcnt(0) drain never waits on it. One barrier per K-iter.
__global__ __launch_bounds__(256) void gemm_kernel(
    const float* __restrict__ x, const unsigned short* __restrict__ Wt,
    unsigned short* __restrict__ xl)
{
    __shared__ __align__(16) unsigned short sA[32 * 256];      // 16 KB
    __shared__ __align__(16) unsigned short sB[2][256 * 32];   // 32 KB

    const int tid  = threadIdx.x;
    const int l    = tid & 63;
    const int wq   = tid >> 6;
    const int quad = l >> 4;
    const int l15  = l & 15;
    const int m0   = blockIdx.x * 32;

    // ---- prologue: stage full A tile (fp32 -> bf16), unit-XOR swizzle ----
    {
        int row = tid >> 3;              // 32 rows, 8 threads/row
        int kb  = (tid & 7) * 32;        // 32 k per thread (128 B coalesced)
        int gm = m0 + row; if (gm > NUM_NODES - 1) gm = NUM_NODES - 1;
        const float* p = x + (size_t)gm * D_IN + kb;
        #pragma unroll
        for (int j = 0; j < 4; ++j) {    // 4 units of 8 bf16
            float4 v0 = *(const float4*)(p + j * 8);
            float4 v1 = *(const float4*)(p + j * 8 + 4);
            bf16x8 av;
            av[0] = (short)f2bf(v0.x); av[1] = (short)f2bf(v0.y);
            av[2] = (short)f2bf(v0.z); av[3] = (short)f2bf(v0.w);
            av[4] = (short)f2bf(v1.x); av[5] = (short)f2bf(v1.y);
            av[6] = (short)f2bf(v1.z); av[7] = (short)f2bf(v1.w);
            int u  = (kb >> 3) + j;                       // unit 0..31
            int us = u ^ (row & 7);                       // bank spread
            *(bf16x8*)(&sA[row * 256 + us * 8]) = av;
        }
    }
    // ---- B chunk 0 into regs ----
    bf16x8 breg[4];
    #pragma unroll
    for (int i = 0; i < 4; ++i) {
        int c = i * 256 + tid, row = c >> 2, g = c & 3;
        breg[i] = *(const bf16x8*)(Wt + row * 256 + g * 8);
    }

    f32x4 acc[2][4];
    #pragma unroll
    for (int i = 0; i < 2; ++i)
        #pragma unroll
        for (int j = 0; j < 4; ++j) acc[i][j] = (f32x4){0.f, 0.f, 0.f, 0.f};

    int buf = 0;
    for (int k0 = 0; k0 < 8; ++k0) {
        // write current B chunk to LDS (waits on its own loads only)
        #pragma unroll
        for (int i = 0; i < 4; ++i) {
            int c = i * 256 + tid, row = c >> 2, g = c & 3;
            int s = g ^ ((row >> 1) & 3);
            *(bf16x8*)(&sB[buf][row * 32 + s * 8]) = breg[i];
        }
        __syncthreads();
        // prefetch next B chunk AFTER barrier (stays in flight over MFMAs)
        if (k0 < 7) {
            #pragma unroll
            for (int i = 0; i < 4; ++i) {
                int c = i * 256 + tid, row = c >> 2, g = c & 3;
                breg[i] = *(const bf16x8*)(Wt + row * 256 + (k0 + 1) * 32 + g * 8);
            }
        }
        // A frags from persistent sA
        bf16x8 af[2];
        #pragma unroll
        for (int mi = 0; mi < 2; ++mi) {
            int r  = mi * 16 + l15;
            int u  = k0 * 4 + quad;
            int us = u ^ (r & 7);
            af[mi] = *(const bf16x8*)(&sA[r * 256 + us * 8]);
        }
        // B frags
        bf16x8 bfr[4];
        #pragma unroll
        for (int ni = 0; ni < 4; ++ni) {
            int r = wq * 64 + ni * 16 + l15;
            int s = quad ^ ((r >> 1) & 3);
            bfr[ni] = *(const bf16x8*)(&sB[buf][r * 32 + s * 8]);
        }
        #pragma unroll
        for (int mi = 0; mi < 2; ++mi)
            #pragma unroll
            for (int ni = 0; ni < 4; ++ni)
                acc[mi][ni] = __builtin_amdgcn_mfma_f32_16x16x32_bf16(
                    af[mi], bfr[ni], acc[mi][ni], 0, 0, 0);
        buf ^= 1;
    }

    // ---- epilogue: LDS bounce (f32, stride 260) -> coalesced 16 B stores ----
    float* bounce = (float*)&sB[0][0];   // 32 KB area >= 16*260*4 B
    for (int half = 0; half < 2; ++half) {
        __syncthreads();                 // prior reads of sB / bounce done
        #pragma unroll
        for (int ni = 0; ni < 4; ++ni) {
            int col = wq * 64 + ni * 16 + l15;
            #pragma unroll
            for (int r = 0; r < 4; ++r)
                bounce[(quad * 4 + r) * 260 + col] = acc[half][ni][r];
        }
        __syncthreads();
        int row = tid >> 4;              // 16 rows
        int c0  = (tid & 15) * 16;       // 16 cols per thread
        int gm  = m0 + half * 16 + row;
        if (gm < NUM_NODES) {
            const float* src = bounce + row * 260 + c0;
            bf16x8 o0, o1;
            #pragma unroll
            for (int j = 0; j < 8; ++j) o0[j] = (short)f2bf(src[j]);
            #pragma unroll
            for (int j = 0; j < 8; ++j) o1[j] = (short)f2bf(src[8 + j]);
            *(bf16x8*)(xl + (size_t)gm * D_OUT + c0)     = o0;
            *(bf16x8*)(xl + (size_t)gm * D_OUT + c0 + 8) = o1;
        }
    }
}

// ---------- 7. edge aggregation (8-deep ILP; bsum fused) ----------
__global__ __launch_bounds__(256) void edge_agg_kernel(
    const unsigned short* __restrict__ xl,
    const int* __restrict__ edge_off, const int* __restrict__ bsE,
    const int* __restrict__ edge_nodes,
    unsigned short* __restrict__ e_feat)
{
    int e = blockIdx.x * 4 + (threadIdx.x >> 6);
    int lane = threadIdx.x & 63;
    if (e >= NUM_EDGES) return;
    int beg = edge_off[e]     + bsE[e >> 8];
    int end = edge_off[e + 1] + bsE[(e + 1) >> 8];
    float ax = 0.f, ay = 0.f, az = 0.f, aw = 0.f;
    int j = beg;
    for (; j + 8 <= end; j += 8) {
        int nn[8];
        #pragma unroll
        for (int t = 0; t < 8; ++t) nn[t] = edge_nodes[j + t];
        ushort4 uu[8];
        #pragma unroll
        for (int t = 0; t < 8; ++t)
            uu[t] = *(const ushort4*)(xl + (size_t)nn[t] * D_OUT + lane * 4);
        #pragma unroll
        for (int t = 0; t < 8; ++t) {
            ax += bf2f(uu[t].x); ay += bf2f(uu[t].y);
            az += bf2f(uu[t].z); aw += bf2f(uu[t].w);
        }
    }
    for (; j < end; ++j) {
        int node = edge_nodes[j];
        ushort4 u = *(const ushort4*)(xl + (size_t)node * D_OUT + lane * 4);
        ax += bf2f(u.x); ay += bf2f(u.y); az += bf2f(u.z); aw += bf2f(u.w);
    }
    float binv = (end > beg) ? 1.0f / (float)(end - beg) : 0.0f;
    ushort4 o;
    o.x = f2bf(ax * binv); o.y = f2bf(ay * binv);
    o.z = f2bf(az * binv); o.w = f2bf(aw * binv);
    *(ushort4*)(e_feat + (size_t)e * D_OUT + lane * 4) = o;
}

// ---------- 8. node aggregation (Dv fused, 8-deep ILP, bsum fused) ----------
__global__ __launch_bounds__(256) void node_agg_kernel(
    const unsigned short* __restrict__ e_feat,
    const int* __restrict__ node_off, const int* __restrict__ bsN,
    const int* __restrict__ node_edges,
    const float* __restrict__ w, const float* __restrict__ bias,
    float* __restrict__ out)
{
    int n = blockIdx.x * 4 + (threadIdx.x >> 6);
    int lane = threadIdx.x & 63;
    if (n >= NUM_NODES) return;
    int beg = node_off[n]     + bsN[n >> 8];
    int end = node_off[n + 1] + bsN[(n + 1) >> 8];
    float ax = 0.f, ay = 0.f, az = 0.f, aw = 0.f;
    float dsum = 0.f;
    int j = beg;
    for (; j + 8 <= end; j += 8) {
        int ee[8];
        #pragma unroll
        for (int t = 0; t < 8; ++t) ee[t] = node_edges[j + t];
        ushort4 uu[8];
        #pragma unroll
        for (int t = 0; t < 8; ++t)
            uu[t] = *(const ushort4*)(e_feat + (size_t)ee[t] * D_OUT + lane * 4);
        float ws[8];
        #pragma unroll
        for (int t = 0; t < 8; ++t) ws[t] = w[ee[t]];
        #pragma unroll
        for (int t = 0; t < 8; ++t) {
            dsum += ws[t];
            ax += bf2f(uu[t].x); ay += bf2f(uu[t].y);
            az += bf2f(uu[t].z); aw += bf2f(uu[t].w);
        }
    }
    for (; j < end; ++j) {
        int e = node_edges[j];
        dsum += w[e];
        ushort4 u = *(const ushort4*)(e_feat + (size_t)e * D_OUT + lane * 4);
        ax += bf2f(u.x); ay += bf2f(u.y); az += bf2f(u.z); aw += bf2f(u.w);
    }
    float dinv = (dsum > 0.0f) ? 1.0f / dsum : 0.0f;
    float4 bv = *(const float4*)(bias + lane * 4);
    float4 o;
    o.x = ax * dinv + bv.x;
    o.y = ay * dinv + bv.y;
    o.z = az * dinv + bv.z;
    o.w = aw * dinv + bv.w;
    *(float4*)(out + (size_t)n * D_OUT + lane * 4) = o;
}

extern "C" void kernel_launch(void* const* d_in, const int* in_sizes, int n_in,
                              void* d_out, int out_size, void* d_ws, size_t ws_size,
                              hipStream_t stream) {
    const float* x    = (const float*)d_in[0];
    const int*   hidx = (const int*)d_in[1];     // [2, NNZ]: row0=node_idx, row1=edge_idx
    const float* w    = (const float*)d_in[2];
    const float* W    = (const float*)d_in[3];
    const float* b    = (const float*)d_in[4];
    const int* node_idx = hidx;
    const int* edge_idx = hidx + NNZ;

    // ---- workspace carve-up ----
    char* ws = (char*)d_ws;
    size_t off = 0;
    auto alloc = [&](size_t bytes) -> void* {
        off = (off + 511) & ~(size_t)511;
        void* p = ws + off;
        off += bytes;
        return p;
    };
    unsigned short* xl     = (unsigned short*)alloc((size_t)NUM_NODES * D_OUT * 2); // 25.6 MB
    unsigned short* e_feat = (unsigned short*)alloc((size_t)NUM_EDGES * D_OUT * 2); // 25.6 MB
    int* Bc         = (int*)alloc(50000 * sizeof(int));
    int* node_cnt   = (int*)alloc(50000 * sizeof(int));
    int* edge_off   = (int*)alloc((NUM_EDGES + 1) * sizeof(int));
    int* node_off   = (int*)alloc((NUM_NODES + 1) * sizeof(int));
    int* edge_nodes = (int*)alloc((size_t)NNZ * sizeof(int));
    int* node_edges = (int*)alloc((size_t)NNZ * sizeof(int));
    unsigned short* Wt = (unsigned short*)alloc(256 * 256 * 2);
    int* bsums    = (int*)alloc(2 * NBLK * sizeof(int));
    int* bsum_off = (int*)alloc(2 * NBLK * sizeof(int));

    // Histogram/prefix scratch ALIASED over xl / e_feat (12.8 MB each; fully
    // consumed by fill_kernel before gemm/edge_agg write xl/e_feat).
    unsigned int* HbE = (unsigned int*)xl;
    unsigned int* HbN = (unsigned int*)e_feat;

    hist_kernel<<<dim3(HB, 2), 256, 0, stream>>>(node_idx, edge_idx, HbE, HbN, W, Wt);
    hreduce_kernel<<<dim3((HWORDS + 255) / 256, 2), 256, 0, stream>>>(HbE, HbN, Bc, node_cnt);
    scan1_kernel<<<dim3(NBLK, 2), 256, 0, stream>>>(Bc, node_cnt, edge_off, node_off, bsums);
    scan2_kernel<<<1, 256, 0, stream>>>(bsums, bsum_off, edge_off, node_off);
    fill_kernel<<<dim3(HB, 2), 256, 0, stream>>>(node_idx, edge_idx, HbE, HbN,
                                                 edge_off, node_off, bsum_off,
                                                 edge_nodes, node_edges);
    gemm_kernel<<<(NUM_NODES + 31) / 32, 256, 0, stream>>>(x, Wt, xl);
    edge_agg_kernel<<<NUM_EDGES / 4, 256, 0, stream>>>(xl, edge_off, bsum_off,
                                                       edge_nodes, e_feat);
    node_agg_kernel<<<NUM_NODES / 4, 256, 0, stream>>>(e_feat, node_off, bsum_off + NBLK,
                                                       node_edges, w, b, (float*)d_out);
}